// Round 1
// baseline (590.077 us; speedup 1.0000x reference)
//
#include <hip/hip_runtime.h>
#include <hip/hip_bf16.h>

// ---------------- problem constants ----------------
#define N_NODES   50000
#define N_EDGES   800000
#define IN_C      256
#define HID_C     128
#define N_GRAPHS  256
#define N_CLASSES 6
#define BN_EPS    1e-5f

// ---------------- utility kernels ----------------

// zero ecnt, cursor, pooled, counts
__global__ void k_init(int* ecnt, int* cursor, float* pooled, float* counts, int n) {
    int i = blockIdx.x * blockDim.x + threadIdx.x;
    if (i < n) { ecnt[i] = 0; cursor[i] = 0; }
    if (i < N_GRAPHS * HID_C) pooled[i] = 0.f;
    if (i < N_GRAPHS) counts[i] = 0.f;
}

__global__ void k_count(const int* __restrict__ col, int* __restrict__ ecnt, int e) {
    int i = blockIdx.x * blockDim.x + threadIdx.x;
    if (i < e) atomicAdd(&ecnt[col[i]], 1);
}

__global__ void k_dinv(const int* __restrict__ ecnt, float* __restrict__ dinv, int n) {
    int i = blockIdx.x * blockDim.x + threadIdx.x;
    if (i < n) dinv[i] = rsqrtf((float)(ecnt[i] + 1));  // +1 self loop
}

// block-level inclusive scan of ecnt -> row_ptr (per-block), block totals -> bsum
__global__ void k_scanA(const int* __restrict__ ecnt, int* __restrict__ row_ptr,
                        int* __restrict__ bsum, int n) {
    __shared__ int s[256];
    int t = threadIdx.x;
    int i = blockIdx.x * 256 + t;
    int v = (i < n) ? ecnt[i] : 0;
    s[t] = v;
    __syncthreads();
    for (int d = 1; d < 256; d <<= 1) {
        int add = (t >= d) ? s[t - d] : 0;
        __syncthreads();
        s[t] += add;
        __syncthreads();
    }
    if (i < n) row_ptr[i] = s[t];               // inclusive for now
    if (t == 255) bsum[blockIdx.x] = s[255];
}

// single block: exclusive scan of bsum -> bsumx  (nb <= 256)
__global__ void k_scanB(const int* __restrict__ bsum, int* __restrict__ bsumx, int nb) {
    __shared__ int s[256];
    int t = threadIdx.x;
    int v = (t < nb) ? bsum[t] : 0;
    s[t] = v;
    __syncthreads();
    for (int d = 1; d < 256; d <<= 1) {
        int add = (t >= d) ? s[t - d] : 0;
        __syncthreads();
        s[t] += add;
        __syncthreads();
    }
    bsumx[t] = s[t] - v;  // exclusive
}

// row_ptr[i] = inclusive - ecnt + block offset  (-> exclusive); row_ptr[n] = e
__global__ void k_scanC(const int* __restrict__ ecnt, int* __restrict__ row_ptr,
                        const int* __restrict__ bsumx, int n, int e) {
    int i = blockIdx.x * 256 + threadIdx.x;
    if (i < n) row_ptr[i] = row_ptr[i] - ecnt[i] + bsumx[blockIdx.x];
    if (i == 0) row_ptr[n] = e;
}

__global__ void k_fill(const int* __restrict__ row, const int* __restrict__ col,
                       const int* __restrict__ row_ptr, int* __restrict__ cursor,
                       int* __restrict__ csr_src, int e) {
    int i = blockIdx.x * blockDim.x + threadIdx.x;
    if (i < e) {
        int c = col[i];
        int pos = row_ptr[c] + atomicAdd(&cursor[c], 1);
        csr_src[pos] = row[i];
    }
}

// ---------------- GEMM: C[M,128] = A[M,K] @ B[K,128], fp32 ----------------
#define BM 128
#define BN 128
#define BK 16

__global__ __launch_bounds__(256) void k_gemm(const float* __restrict__ A,
                                              const float* __restrict__ B,
                                              float* __restrict__ C, int M, int K) {
    __shared__ float As[BK][BM + 4];
    __shared__ float Bs[BK][BN];
    int tid = threadIdx.x;
    int tx = tid & 15;   // 0..15 col group
    int ty = tid >> 4;   // 0..15 row group
    int row0 = blockIdx.x * BM;
    float acc[8][8] = {};

    for (int k0 = 0; k0 < K; k0 += BK) {
        // A tile: 128 rows x 16 k  (512 float4 slots, 2 per thread)
#pragma unroll
        for (int it = 0; it < 2; ++it) {
            int s = tid + it * 256;
            int r = s >> 2;
            int kc = (s & 3) * 4;
            float4 v = make_float4(0.f, 0.f, 0.f, 0.f);
            int gr = row0 + r;
            if (gr < M) v = *reinterpret_cast<const float4*>(&A[(size_t)gr * K + k0 + kc]);
            As[kc + 0][r] = v.x;
            As[kc + 1][r] = v.y;
            As[kc + 2][r] = v.z;
            As[kc + 3][r] = v.w;
        }
        // B tile: 16 k x 128 cols
#pragma unroll
        for (int it = 0; it < 2; ++it) {
            int s = tid + it * 256;
            int kr = s >> 5;
            int cc = (s & 31) * 4;
            *reinterpret_cast<float4*>(&Bs[kr][cc]) =
                *reinterpret_cast<const float4*>(&B[(size_t)(k0 + kr) * 128 + cc]);
        }
        __syncthreads();
#pragma unroll
        for (int kk = 0; kk < BK; ++kk) {
            float a[8], b[8];
            *reinterpret_cast<float4*>(&a[0]) = *reinterpret_cast<float4*>(&As[kk][ty * 8]);
            *reinterpret_cast<float4*>(&a[4]) = *reinterpret_cast<float4*>(&As[kk][ty * 8 + 4]);
            *reinterpret_cast<float4*>(&b[0]) = *reinterpret_cast<float4*>(&Bs[kk][tx * 8]);
            *reinterpret_cast<float4*>(&b[4]) = *reinterpret_cast<float4*>(&Bs[kk][tx * 8 + 4]);
#pragma unroll
            for (int i = 0; i < 8; ++i)
#pragma unroll
                for (int j = 0; j < 8; ++j)
                    acc[i][j] = fmaf(a[i], b[j], acc[i][j]);
        }
        __syncthreads();
    }
#pragma unroll
    for (int i = 0; i < 8; ++i) {
        int gr = row0 + ty * 8 + i;
        if (gr < M) {
            float4* out = reinterpret_cast<float4*>(&C[(size_t)gr * 128 + tx * 8]);
            out[0] = *reinterpret_cast<float4*>(&acc[i][0]);
            out[1] = *reinterpret_cast<float4*>(&acc[i][4]);
        }
    }
}

// ---------------- aggregate + bias + BN + ReLU ----------------
// one node per block, 128 threads = channels
__global__ __launch_bounds__(128) void k_agg(const float* __restrict__ h,
                                             const int* __restrict__ row_ptr,
                                             const int* __restrict__ csr_src,
                                             const float* __restrict__ dinv,
                                             const float* __restrict__ bias,
                                             const float* __restrict__ gam,
                                             const float* __restrict__ bet,
                                             const float* __restrict__ mu,
                                             const float* __restrict__ var,
                                             float* __restrict__ out) {
    int vtx = blockIdx.x;
    int ch = threadIdx.x;
    int beg = row_ptr[vtx];
    int end = row_ptr[vtx + 1];
    float acc = 0.f;
    for (int e = beg; e < end; ++e) {
        int src = csr_src[e];
        float w = dinv[src];
        acc = fmaf(h[(size_t)src * 128 + ch], w, acc);
    }
    float dv = dinv[vtx];
    float self = h[(size_t)vtx * 128 + ch];
    float val = acc * dv + self * dv * dv + bias[ch];
    float scale = gam[ch] * rsqrtf(var[ch] + BN_EPS);
    val = (val - mu[ch]) * scale + bet[ch];
    out[(size_t)vtx * 128 + ch] = fmaxf(val, 0.f);
}

// ---------------- pooling ----------------
__global__ void k_cnt(const int* __restrict__ batch, float* __restrict__ counts, int n) {
    int i = blockIdx.x * blockDim.x + threadIdx.x;
    if (i < n) atomicAdd(&counts[batch[i]], 1.0f);
}

// 64 nodes per block, run-length accumulate (batch sorted), flush via atomics
__global__ __launch_bounds__(128) void k_pool(const float* __restrict__ h,
                                              const int* __restrict__ batch,
                                              float* __restrict__ pooled, int n) {
    int ch = threadIdx.x;
    int n0 = blockIdx.x * 64;
    if (n0 >= n) return;
    int n1 = min(n0 + 64, n);
    float acc = 0.f;
    int cur = batch[n0];
    for (int i = n0; i < n1; ++i) {
        int g = batch[i];
        if (g != cur) {
            atomicAdd(&pooled[cur * 128 + ch], acc);
            acc = 0.f;
            cur = g;
        }
        acc += h[(size_t)i * 128 + ch];
    }
    atomicAdd(&pooled[cur * 128 + ch], acc);
}

__global__ void k_final(const float* __restrict__ pooled, const float* __restrict__ counts,
                        const float* __restrict__ lw, const float* __restrict__ lb,
                        float* __restrict__ out) {
    int t = blockIdx.x * blockDim.x + threadIdx.x;
    if (t >= N_GRAPHS * N_CLASSES) return;
    int g = t / N_CLASSES, cls = t % N_CLASSES;
    float inv = 1.0f / fmaxf(counts[g], 1.0f);
    float acc = 0.f;
    for (int k = 0; k < 128; ++k)
        acc += pooled[g * 128 + k] * lw[k * N_CLASSES + cls];
    out[t] = acc * inv + lb[cls];
}

// ---------------- launch ----------------
extern "C" void kernel_launch(void* const* d_in, const int* in_sizes, int n_in,
                              void* d_out, int out_size, void* d_ws, size_t ws_size,
                              hipStream_t stream) {
    const float* x      = (const float*)d_in[0];
    const int*   ei     = (const int*)d_in[1];
    const int*   batch  = (const int*)d_in[2];
    const float* W0  = (const float*)d_in[3];
    const float* b0  = (const float*)d_in[4];
    const float* g0  = (const float*)d_in[5];
    const float* bt0 = (const float*)d_in[6];
    const float* m0  = (const float*)d_in[7];
    const float* v0  = (const float*)d_in[8];
    const float* W1  = (const float*)d_in[9];
    const float* b1  = (const float*)d_in[10];
    const float* g1  = (const float*)d_in[11];
    const float* bt1 = (const float*)d_in[12];
    const float* m1  = (const float*)d_in[13];
    const float* v1  = (const float*)d_in[14];
    const float* W2  = (const float*)d_in[15];
    const float* b2  = (const float*)d_in[16];
    const float* g2  = (const float*)d_in[17];
    const float* bt2 = (const float*)d_in[18];
    const float* m2  = (const float*)d_in[19];
    const float* v2  = (const float*)d_in[20];
    const float* lw  = (const float*)d_in[21];
    const float* lb  = (const float*)d_in[22];
    float* out = (float*)d_out;

    const int N = in_sizes[2];          // 50000
    const int E = in_sizes[1] / 2;      // 800000
    const int* row = ei;
    const int* col = ei + E;

    // workspace layout
    char* ws = (char*)d_ws;
    size_t off = 0;
    auto alloc = [&](size_t bytes) {
        void* p = ws + off;
        off += (bytes + 511) & ~(size_t)511;
        return p;
    };
    float* hA      = (float*)alloc((size_t)N * 128 * 4);
    float* hB      = (float*)alloc((size_t)N * 128 * 4);
    int*   ecnt    = (int*)alloc((size_t)N * 4);
    int*   cursor  = (int*)alloc((size_t)N * 4);
    int*   row_ptr = (int*)alloc((size_t)(N + 1) * 4);
    int*   csr_src = (int*)alloc((size_t)E * 4);
    float* dinv    = (float*)alloc((size_t)N * 4);
    int*   bsum    = (int*)alloc(256 * 4);
    int*   bsumx   = (int*)alloc(256 * 4);
    float* pooled  = (float*)alloc((size_t)N_GRAPHS * 128 * 4);
    float* counts  = (float*)alloc((size_t)N_GRAPHS * 4);

    const int NB_n = (N + 255) / 256;   // 196
    const int NB_e = (E + 255) / 256;   // 3125

    k_init<<<NB_n, 256, 0, stream>>>(ecnt, cursor, pooled, counts, N);
    k_count<<<NB_e, 256, 0, stream>>>(col, ecnt, E);
    k_dinv<<<NB_n, 256, 0, stream>>>(ecnt, dinv, N);
    k_scanA<<<NB_n, 256, 0, stream>>>(ecnt, row_ptr, bsum, N);
    k_scanB<<<1, 256, 0, stream>>>(bsum, bsumx, NB_n);
    k_scanC<<<NB_n, 256, 0, stream>>>(ecnt, row_ptr, bsumx, N, E);
    k_fill<<<NB_e, 256, 0, stream>>>(row, col, row_ptr, cursor, csr_src, E);

    const int GB = (N + BM - 1) / BM;   // 391

    // layer 0: x (K=256) -> hB -> hA
    k_gemm<<<GB, 256, 0, stream>>>(x, W0, hB, N, IN_C);
    k_agg<<<N, 128, 0, stream>>>(hB, row_ptr, csr_src, dinv, b0, g0, bt0, m0, v0, hA);
    // layer 1: hA (K=128) -> hB -> hA
    k_gemm<<<GB, 256, 0, stream>>>(hA, W1, hB, N, HID_C);
    k_agg<<<N, 128, 0, stream>>>(hB, row_ptr, csr_src, dinv, b1, g1, bt1, m1, v1, hA);
    // layer 2
    k_gemm<<<GB, 256, 0, stream>>>(hA, W2, hB, N, HID_C);
    k_agg<<<N, 128, 0, stream>>>(hB, row_ptr, csr_src, dinv, b2, g2, bt2, m2, v2, hA);

    // pooling + classifier
    k_cnt<<<NB_n, 256, 0, stream>>>(batch, counts, N);
    k_pool<<<(N + 63) / 64, 128, 0, stream>>>(hA, batch, pooled, N);
    k_final<<<(N_GRAPHS * N_CLASSES + 255) / 256, 256, 0, stream>>>(pooled, counts, lw, lb, out);
}

// Round 2
// 414.502 us; speedup vs baseline: 1.4236x; 1.4236x over previous
//
#include <hip/hip_runtime.h>
#include <hip/hip_bf16.h>

// ---------------- problem constants ----------------
#define N_NODES   50000
#define N_EDGES   800000
#define IN_C      256
#define HID_C     128
#define N_GRAPHS  256
#define N_CLASSES 6
#define BN_EPS    1e-5f

using bf16x8 = __attribute__((ext_vector_type(8))) short;
using f32x4  = __attribute__((ext_vector_type(4))) float;

__device__ __forceinline__ ushort f2bf(float f) {
    union { float f; unsigned u; } v; v.f = f;
    unsigned r = v.u + 0x7fffu + ((v.u >> 16) & 1u);
    return (ushort)(r >> 16);
}
__device__ __forceinline__ float bflo(unsigned u) {
    union { unsigned u; float f; } v; v.u = u << 16; return v.f;
}
__device__ __forceinline__ float bfhi(unsigned u) {
    union { unsigned u; float f; } v; v.u = u & 0xffff0000u; return v.f;
}

// ---------------- CSR build ----------------
__global__ void k_init(int* ecnt, int* cursor, float* pooled, float* counts, int n) {
    int i = blockIdx.x * blockDim.x + threadIdx.x;
    if (i < n) { ecnt[i] = 0; cursor[i] = 0; }
    if (i < N_GRAPHS * HID_C) pooled[i] = 0.f;
    if (i < N_GRAPHS) counts[i] = 0.f;
}

__global__ void k_count(const int* __restrict__ col, int* __restrict__ ecnt, int e) {
    int i = blockIdx.x * blockDim.x + threadIdx.x;
    if (i < e) atomicAdd(&ecnt[col[i]], 1);
}

__global__ void k_dinv(const int* __restrict__ ecnt, float* __restrict__ dinv, int n) {
    int i = blockIdx.x * blockDim.x + threadIdx.x;
    if (i < n) dinv[i] = rsqrtf((float)(ecnt[i] + 1));  // +1 self loop
}

__global__ void k_scanA(const int* __restrict__ ecnt, int* __restrict__ row_ptr,
                        int* __restrict__ bsum, int n) {
    __shared__ int s[256];
    int t = threadIdx.x;
    int i = blockIdx.x * 256 + t;
    int v = (i < n) ? ecnt[i] : 0;
    s[t] = v;
    __syncthreads();
    for (int d = 1; d < 256; d <<= 1) {
        int add = (t >= d) ? s[t - d] : 0;
        __syncthreads();
        s[t] += add;
        __syncthreads();
    }
    if (i < n) row_ptr[i] = s[t];
    if (t == 255) bsum[blockIdx.x] = s[255];
}

__global__ void k_scanB(const int* __restrict__ bsum, int* __restrict__ bsumx, int nb) {
    __shared__ int s[256];
    int t = threadIdx.x;
    int v = (t < nb) ? bsum[t] : 0;
    s[t] = v;
    __syncthreads();
    for (int d = 1; d < 256; d <<= 1) {
        int add = (t >= d) ? s[t - d] : 0;
        __syncthreads();
        s[t] += add;
        __syncthreads();
    }
    bsumx[t] = s[t] - v;
}

__global__ void k_scanC(const int* __restrict__ ecnt, int* __restrict__ row_ptr,
                        const int* __restrict__ bsumx, int n, int e) {
    int i = blockIdx.x * 256 + threadIdx.x;
    if (i < n) row_ptr[i] = row_ptr[i] - ecnt[i] + bsumx[blockIdx.x];
    if (i == 0) row_ptr[n] = e;
}

__global__ void k_fill(const int* __restrict__ row, const int* __restrict__ col,
                       const int* __restrict__ row_ptr, int* __restrict__ cursor,
                       int* __restrict__ csr_src, int e) {
    int i = blockIdx.x * blockDim.x + threadIdx.x;
    if (i < e) {
        int c = col[i];
        int pos = row_ptr[c] + atomicAdd(&cursor[c], 1);
        csr_src[pos] = row[i];
    }
}

// ---------------- weight prep: cast + transpose  Wt[co][k] = bf16(W[k][co]) ----------------
__global__ void k_prepW(const float* __restrict__ W, ushort* __restrict__ Wt, int K) {
    int t = blockIdx.x * blockDim.x + threadIdx.x;
    if (t >= 128 * K) return;
    int co = t / K, k = t % K;
    Wt[t] = f2bf(W[(size_t)k * 128 + co]);
}

// ---------------- MFMA GEMM: Cbf[M,128] = A[M,K] @ W[K,128]  (bf16 in, bf16 out) ----------
// block = 256 threads = 4 waves; each wave does 16 rows x 128 cols; K fully in LDS (swizzled)
template <int K, bool AFP32>
__global__ __launch_bounds__(256) void k_gemmbf(const void* __restrict__ Av,
                                                const ushort* __restrict__ Wt,
                                                ushort* __restrict__ Cbf, int M) {
    extern __shared__ char smem[];  // K*128*2 bytes, layout: [col][k] bf16, 16B-XOR swizzled
    const int tid = threadIdx.x;
    constexpr int CPC = K / 8;          // 16B chunks per col
    constexpr int NCH = 128 * CPC;
    for (int c = tid; c < NCH; c += 256) {
        int col = c / CPC, kg = c % CPC;
        float4 v = *reinterpret_cast<const float4*>(Wt + (size_t)col * K + kg * 8);
        int dst = col * (K * 2) + ((kg * 16) ^ ((col & 7) << 4));
        *reinterpret_cast<float4*>(smem + dst) = v;
    }
    __syncthreads();

    const int wave = tid >> 6, lane = tid & 63;
    const int l15 = lane & 15, lg = lane >> 4;
    const int row = blockIdx.x * 64 + wave * 16 + l15;
    const bool rok = (row < M);

    f32x4 acc[8] = {};

#pragma unroll
    for (int ks = 0; ks < K / 32; ++ks) {
        bf16x8 a;
        if (AFP32) {
            const float* Ap = (const float*)Av + (size_t)row * K + ks * 32 + lg * 8;
            float4 f0, f1;
            if (rok) {
                f0 = *reinterpret_cast<const float4*>(Ap);
                f1 = *reinterpret_cast<const float4*>(Ap + 4);
            } else {
                f0 = make_float4(0, 0, 0, 0); f1 = f0;
            }
            a[0] = (short)f2bf(f0.x); a[1] = (short)f2bf(f0.y);
            a[2] = (short)f2bf(f0.z); a[3] = (short)f2bf(f0.w);
            a[4] = (short)f2bf(f1.x); a[5] = (short)f2bf(f1.y);
            a[6] = (short)f2bf(f1.z); a[7] = (short)f2bf(f1.w);
        } else {
            if (rok) {
                const ushort* Ap = (const ushort*)Av + (size_t)row * K + ks * 32 + lg * 8;
                a = *reinterpret_cast<const bf16x8*>(Ap);
            } else {
#pragma unroll
                for (int j = 0; j < 8; ++j) a[j] = 0;
            }
        }
#pragma unroll
        for (int cf = 0; cf < 8; ++cf) {
            int col = cf * 16 + l15;
            int off = col * (K * 2) + ((ks * 64 + lg * 16) ^ ((col & 7) << 4));
            bf16x8 b = *reinterpret_cast<const bf16x8*>(smem + off);
            acc[cf] = __builtin_amdgcn_mfma_f32_16x16x32_bf16(a, b, acc[cf], 0, 0, 0);
        }
    }

    // C/D layout: col = lane&15, row = (lane>>4)*4 + i   [m89-verified]
#pragma unroll
    for (int cf = 0; cf < 8; ++cf) {
        int col = cf * 16 + l15;
#pragma unroll
        for (int i = 0; i < 4; ++i) {
            int r = blockIdx.x * 64 + wave * 16 + lg * 4 + i;
            if (r < M) Cbf[(size_t)r * 128 + col] = f2bf(acc[cf][i]);
        }
    }
}

// ---------------- aggregate + bias + BN + ReLU  (bf16 h -> bf16 out) ----------------
// 4 waves/block, one node per wave, lane handles 2 channels
__global__ __launch_bounds__(256) void k_aggbf(const ushort* __restrict__ h,
                                               const int* __restrict__ row_ptr,
                                               const int* __restrict__ csr_src,
                                               const float* __restrict__ dinv,
                                               const float* __restrict__ bias,
                                               const float* __restrict__ gam,
                                               const float* __restrict__ bet,
                                               const float* __restrict__ mu,
                                               const float* __restrict__ var,
                                               ushort* __restrict__ out, int n) {
    int wave = threadIdx.x >> 6, lane = threadIdx.x & 63;
    int vtx = blockIdx.x * 4 + wave;
    if (vtx >= n) return;
    int c0 = lane * 2;
    int beg = row_ptr[vtx], end = row_ptr[vtx + 1];
    float a0 = 0.f, a1 = 0.f;
    int e = beg;
    for (; e + 1 < end; e += 2) {
        int s0 = csr_src[e], s1 = csr_src[e + 1];
        float w0 = dinv[s0], w1 = dinv[s1];
        unsigned u0 = *reinterpret_cast<const unsigned*>(h + (size_t)s0 * 128 + c0);
        unsigned u1 = *reinterpret_cast<const unsigned*>(h + (size_t)s1 * 128 + c0);
        a0 = fmaf(bflo(u0), w0, a0); a1 = fmaf(bfhi(u0), w0, a1);
        a0 = fmaf(bflo(u1), w1, a0); a1 = fmaf(bfhi(u1), w1, a1);
    }
    if (e < end) {
        int s0 = csr_src[e];
        float w0 = dinv[s0];
        unsigned u0 = *reinterpret_cast<const unsigned*>(h + (size_t)s0 * 128 + c0);
        a0 = fmaf(bflo(u0), w0, a0); a1 = fmaf(bfhi(u0), w0, a1);
    }
    float dv = dinv[vtx];
    unsigned us = *reinterpret_cast<const unsigned*>(h + (size_t)vtx * 128 + c0);
    float v0 = a0 * dv + bflo(us) * dv * dv + bias[c0];
    float v1 = a1 * dv + bfhi(us) * dv * dv + bias[c0 + 1];
    float sc0 = gam[c0] * rsqrtf(var[c0] + BN_EPS);
    float sc1 = gam[c0 + 1] * rsqrtf(var[c0 + 1] + BN_EPS);
    v0 = fmaxf((v0 - mu[c0]) * sc0 + bet[c0], 0.f);
    v1 = fmaxf((v1 - mu[c0 + 1]) * sc1 + bet[c0 + 1], 0.f);
    unsigned packed = (unsigned)f2bf(v0) | ((unsigned)f2bf(v1) << 16);
    *reinterpret_cast<unsigned*>(out + (size_t)vtx * 128 + c0) = packed;
}

// ---------------- pooling ----------------
__global__ void k_cnt(const int* __restrict__ batch, float* __restrict__ counts, int n) {
    int i = blockIdx.x * blockDim.x + threadIdx.x;
    if (i < n) atomicAdd(&counts[batch[i]], 1.0f);
}

// 64 nodes per block, lane handles 2 channels; run-length accumulate (batch sorted)
__global__ __launch_bounds__(64) void k_pool(const ushort* __restrict__ h,
                                             const int* __restrict__ batch,
                                             float* __restrict__ pooled, int n) {
    int lane = threadIdx.x;
    int c0 = lane * 2;
    int n0 = blockIdx.x * 64;
    if (n0 >= n) return;
    int n1 = min(n0 + 64, n);
    float a0 = 0.f, a1 = 0.f;
    int cur = batch[n0];
    for (int i = n0; i < n1; ++i) {
        int g = batch[i];
        if (g != cur) {
            atomicAdd(&pooled[cur * 128 + c0], a0);
            atomicAdd(&pooled[cur * 128 + c0 + 1], a1);
            a0 = 0.f; a1 = 0.f;
            cur = g;
        }
        unsigned u = *reinterpret_cast<const unsigned*>(h + (size_t)i * 128 + c0);
        a0 += bflo(u); a1 += bfhi(u);
    }
    atomicAdd(&pooled[cur * 128 + c0], a0);
    atomicAdd(&pooled[cur * 128 + c0 + 1], a1);
}

__global__ void k_final(const float* __restrict__ pooled, const float* __restrict__ counts,
                        const float* __restrict__ lw, const float* __restrict__ lb,
                        float* __restrict__ out) {
    int t = blockIdx.x * blockDim.x + threadIdx.x;
    if (t >= N_GRAPHS * N_CLASSES) return;
    int g = t / N_CLASSES, cls = t % N_CLASSES;
    float inv = 1.0f / fmaxf(counts[g], 1.0f);
    float acc = 0.f;
    for (int k = 0; k < 128; ++k)
        acc += pooled[g * 128 + k] * lw[k * N_CLASSES + cls];
    out[t] = acc * inv + lb[cls];
}

// ---------------- launch ----------------
extern "C" void kernel_launch(void* const* d_in, const int* in_sizes, int n_in,
                              void* d_out, int out_size, void* d_ws, size_t ws_size,
                              hipStream_t stream) {
    const float* x      = (const float*)d_in[0];
    const int*   ei     = (const int*)d_in[1];
    const int*   batch  = (const int*)d_in[2];
    const float* W0  = (const float*)d_in[3];
    const float* b0  = (const float*)d_in[4];
    const float* g0  = (const float*)d_in[5];
    const float* bt0 = (const float*)d_in[6];
    const float* m0  = (const float*)d_in[7];
    const float* v0  = (const float*)d_in[8];
    const float* W1  = (const float*)d_in[9];
    const float* b1  = (const float*)d_in[10];
    const float* g1  = (const float*)d_in[11];
    const float* bt1 = (const float*)d_in[12];
    const float* m1  = (const float*)d_in[13];
    const float* v1  = (const float*)d_in[14];
    const float* W2  = (const float*)d_in[15];
    const float* b2  = (const float*)d_in[16];
    const float* g2  = (const float*)d_in[17];
    const float* bt2 = (const float*)d_in[18];
    const float* m2  = (const float*)d_in[19];
    const float* v2  = (const float*)d_in[20];
    const float* lw  = (const float*)d_in[21];
    const float* lb  = (const float*)d_in[22];
    float* out = (float*)d_out;

    const int N = in_sizes[2];          // 50000
    const int E = in_sizes[1] / 2;      // 800000
    const int* row = ei;
    const int* col = ei + E;

    char* ws = (char*)d_ws;
    size_t off = 0;
    auto alloc = [&](size_t bytes) {
        void* p = ws + off;
        off += (bytes + 511) & ~(size_t)511;
        return p;
    };
    ushort* hA     = (ushort*)alloc((size_t)N * 128 * 2);   // bf16 activations
    ushort* hB     = (ushort*)alloc((size_t)N * 128 * 2);
    ushort* Wt0    = (ushort*)alloc((size_t)128 * IN_C * 2);
    ushort* Wt1    = (ushort*)alloc((size_t)128 * HID_C * 2);
    ushort* Wt2    = (ushort*)alloc((size_t)128 * HID_C * 2);
    int*   ecnt    = (int*)alloc((size_t)N * 4);
    int*   cursor  = (int*)alloc((size_t)N * 4);
    int*   row_ptr = (int*)alloc((size_t)(N + 1) * 4);
    int*   csr_src = (int*)alloc((size_t)E * 4);
    float* dinv    = (float*)alloc((size_t)N * 4);
    int*   bsum    = (int*)alloc(256 * 4);
    int*   bsumx   = (int*)alloc(256 * 4);
    float* pooled  = (float*)alloc((size_t)N_GRAPHS * 128 * 4);
    float* counts  = (float*)alloc((size_t)N_GRAPHS * 4);

    const int NB_n = (N + 255) / 256;   // 196
    const int NB_e = (E + 255) / 256;   // 3125

    k_init<<<NB_n, 256, 0, stream>>>(ecnt, cursor, pooled, counts, N);
    k_count<<<NB_e, 256, 0, stream>>>(col, ecnt, E);
    k_dinv<<<NB_n, 256, 0, stream>>>(ecnt, dinv, N);
    k_scanA<<<NB_n, 256, 0, stream>>>(ecnt, row_ptr, bsum, N);
    k_scanB<<<1, 256, 0, stream>>>(bsum, bsumx, NB_n);
    k_scanC<<<NB_n, 256, 0, stream>>>(ecnt, row_ptr, bsumx, N, E);
    k_fill<<<NB_e, 256, 0, stream>>>(row, col, row_ptr, cursor, csr_src, E);

    k_prepW<<<(128 * IN_C + 255) / 256, 256, 0, stream>>>(W0, Wt0, IN_C);
    k_prepW<<<(128 * HID_C + 255) / 256, 256, 0, stream>>>(W1, Wt1, HID_C);
    k_prepW<<<(128 * HID_C + 255) / 256, 256, 0, stream>>>(W2, Wt2, HID_C);

    const int GB = (N + 63) / 64;       // 782
    const int AB = (N + 3) / 4;         // 12500

    // layer 0: x fp32 (K=256) -> hB bf16 -> hA bf16
    k_gemmbf<IN_C, true><<<GB, 256, IN_C * 128 * 2, stream>>>(x, Wt0, hB, N);
    k_aggbf<<<AB, 256, 0, stream>>>(hB, row_ptr, csr_src, dinv, b0, g0, bt0, m0, v0, hA, N);
    // layer 1
    k_gemmbf<HID_C, false><<<GB, 256, HID_C * 128 * 2, stream>>>(hA, Wt1, hB, N);
    k_aggbf<<<AB, 256, 0, stream>>>(hB, row_ptr, csr_src, dinv, b1, g1, bt1, m1, v1, hA, N);
    // layer 2
    k_gemmbf<HID_C, false><<<GB, 256, HID_C * 128 * 2, stream>>>(hA, Wt2, hB, N);
    k_aggbf<<<AB, 256, 0, stream>>>(hB, row_ptr, csr_src, dinv, b2, g2, bt2, m2, v2, hA, N);

    // pooling + classifier
    k_cnt<<<NB_n, 256, 0, stream>>>(batch, counts, N);
    k_pool<<<(N + 63) / 64, 64, 0, stream>>>(hA, batch, pooled, N);
    k_final<<<(N_GRAPHS * N_CLASSES + 255) / 256, 256, 0, stream>>>(pooled, counts, lw, lb, out);
}

// Round 3
// 350.771 us; speedup vs baseline: 1.6822x; 1.1817x over previous
//
#include <hip/hip_runtime.h>
#include <hip/hip_bf16.h>

// ---------------- problem constants ----------------
#define N_NODES   50000
#define N_EDGES   800000
#define IN_C      256
#define HID_C     128
#define N_GRAPHS  256
#define N_CLASSES 6
#define BN_EPS    1e-5f

using bf16x8 = __attribute__((ext_vector_type(8))) short;
using f32x4  = __attribute__((ext_vector_type(4))) float;

__device__ __forceinline__ ushort f2bf(float f) {
    union { float f; unsigned u; } v; v.f = f;
    unsigned r = v.u + 0x7fffu + ((v.u >> 16) & 1u);
    return (ushort)(r >> 16);
}
__device__ __forceinline__ float bflo(unsigned u) {
    union { unsigned u; float f; } v; v.u = u << 16; return v.f;
}
__device__ __forceinline__ float bfhi(unsigned u) {
    union { unsigned u; float f; } v; v.u = u & 0xffff0000u; return v.f;
}

// ---------------- CSR build ----------------
__global__ void k_init(int* ecnt, int* cursor, float* pooled, int n) {
    int i = blockIdx.x * blockDim.x + threadIdx.x;
    if (i < n) { ecnt[i] = 0; cursor[i] = 0; }
    if (i < N_GRAPHS * HID_C) pooled[i] = 0.f;
}

__global__ void k_count(const int* __restrict__ col, int* __restrict__ ecnt, int e) {
    int i = blockIdx.x * blockDim.x + threadIdx.x;
    if (i < e) atomicAdd(&ecnt[col[i]], 1);
}

__global__ void k_dinv(const int* __restrict__ ecnt, float* __restrict__ dinv, int n) {
    int i = blockIdx.x * blockDim.x + threadIdx.x;
    if (i < n) dinv[i] = rsqrtf((float)(ecnt[i] + 1));  // +1 self loop
}

__global__ void k_scanA(const int* __restrict__ ecnt, int* __restrict__ row_ptr,
                        int* __restrict__ bsum, int n) {
    __shared__ int s[256];
    int t = threadIdx.x;
    int i = blockIdx.x * 256 + t;
    int v = (i < n) ? ecnt[i] : 0;
    s[t] = v;
    __syncthreads();
    for (int d = 1; d < 256; d <<= 1) {
        int add = (t >= d) ? s[t - d] : 0;
        __syncthreads();
        s[t] += add;
        __syncthreads();
    }
    if (i < n) row_ptr[i] = s[t];
    if (t == 255) bsum[blockIdx.x] = s[255];
}

__global__ void k_scanB(const int* __restrict__ bsum, int* __restrict__ bsumx, int nb) {
    __shared__ int s[256];
    int t = threadIdx.x;
    int v = (t < nb) ? bsum[t] : 0;
    s[t] = v;
    __syncthreads();
    for (int d = 1; d < 256; d <<= 1) {
        int add = (t >= d) ? s[t - d] : 0;
        __syncthreads();
        s[t] += add;
        __syncthreads();
    }
    bsumx[t] = s[t] - v;
}

__global__ void k_scanC(const int* __restrict__ ecnt, int* __restrict__ row_ptr,
                        const int* __restrict__ bsumx, int n, int e) {
    int i = blockIdx.x * 256 + threadIdx.x;
    if (i < n) row_ptr[i] = row_ptr[i] - ecnt[i] + bsumx[blockIdx.x];
    if (i == 0) row_ptr[n] = e;
}

__global__ void k_fill(const int* __restrict__ row, const int* __restrict__ col,
                       const int* __restrict__ row_ptr, int* __restrict__ cursor,
                       int* __restrict__ csr_src, int e) {
    int i = blockIdx.x * blockDim.x + threadIdx.x;
    if (i < e) {
        int c = col[i];
        int pos = row_ptr[c] + atomicAdd(&cursor[c], 1);
        csr_src[pos] = row[i];
    }
}

// ---------------- weight prep: cast + transpose  Wt[co][k] = bf16(W[k][co]) ----------------
__global__ void k_prepW(const float* __restrict__ W, ushort* __restrict__ Wt, int K) {
    int t = blockIdx.x * blockDim.x + threadIdx.x;
    if (t >= 128 * K) return;
    int co = t / K, k = t % K;
    Wt[t] = f2bf(W[(size_t)k * 128 + co]);
}

// ---------------- MFMA GEMM: Cbf[M,128] = A[M,K] @ W[K,128]  (bf16 in, bf16 out) ----------
// block = 256 threads = 4 waves; each wave does 16 rows x 128 cols; K fully in LDS (swizzled)
template <int K, bool AFP32>
__global__ __launch_bounds__(256) void k_gemmbf(const void* __restrict__ Av,
                                                const ushort* __restrict__ Wt,
                                                ushort* __restrict__ Cbf, int M) {
    extern __shared__ char smem[];  // K*128*2 bytes, layout: [col][k] bf16, 16B-XOR swizzled
    const int tid = threadIdx.x;
    constexpr int CPC = K / 8;          // 16B chunks per col
    constexpr int NCH = 128 * CPC;
    for (int c = tid; c < NCH; c += 256) {
        int col = c / CPC, kg = c % CPC;
        float4 v = *reinterpret_cast<const float4*>(Wt + (size_t)col * K + kg * 8);
        int dst = col * (K * 2) + ((kg * 16) ^ ((col & 7) << 4));
        *reinterpret_cast<float4*>(smem + dst) = v;
    }
    __syncthreads();

    const int wave = tid >> 6, lane = tid & 63;
    const int l15 = lane & 15, lg = lane >> 4;
    const int row = blockIdx.x * 64 + wave * 16 + l15;
    const bool rok = (row < M);

    f32x4 acc[8] = {};

#pragma unroll
    for (int ks = 0; ks < K / 32; ++ks) {
        bf16x8 a;
        if (AFP32) {
            const float* Ap = (const float*)Av + (size_t)row * K + ks * 32 + lg * 8;
            float4 f0, f1;
            if (rok) {
                f0 = *reinterpret_cast<const float4*>(Ap);
                f1 = *reinterpret_cast<const float4*>(Ap + 4);
            } else {
                f0 = make_float4(0, 0, 0, 0); f1 = f0;
            }
            a[0] = (short)f2bf(f0.x); a[1] = (short)f2bf(f0.y);
            a[2] = (short)f2bf(f0.z); a[3] = (short)f2bf(f0.w);
            a[4] = (short)f2bf(f1.x); a[5] = (short)f2bf(f1.y);
            a[6] = (short)f2bf(f1.z); a[7] = (short)f2bf(f1.w);
        } else {
            if (rok) {
                const ushort* Ap = (const ushort*)Av + (size_t)row * K + ks * 32 + lg * 8;
                a = *reinterpret_cast<const bf16x8*>(Ap);
            } else {
#pragma unroll
                for (int j = 0; j < 8; ++j) a[j] = 0;
            }
        }
#pragma unroll
        for (int cf = 0; cf < 8; ++cf) {
            int col = cf * 16 + l15;
            int off = col * (K * 2) + ((ks * 64 + lg * 16) ^ ((col & 7) << 4));
            bf16x8 b = *reinterpret_cast<const bf16x8*>(smem + off);
            acc[cf] = __builtin_amdgcn_mfma_f32_16x16x32_bf16(a, b, acc[cf], 0, 0, 0);
        }
    }

    // C/D layout: col = lane&15, row = (lane>>4)*4 + i   [m89-verified]
#pragma unroll
    for (int cf = 0; cf < 8; ++cf) {
        int col = cf * 16 + l15;
#pragma unroll
        for (int i = 0; i < 4; ++i) {
            int r = blockIdx.x * 64 + wave * 16 + lg * 4 + i;
            if (r < M) Cbf[(size_t)r * 128 + col] = f2bf(acc[cf][i]);
        }
    }
}

// ---------------- aggregate + bias + BN + ReLU  (bf16 h -> bf16 out) ----------------
// 4 waves/block, one node per wave, lane handles 2 channels
__global__ __launch_bounds__(256) void k_aggbf(const ushort* __restrict__ h,
                                               const int* __restrict__ row_ptr,
                                               const int* __restrict__ csr_src,
                                               const float* __restrict__ dinv,
                                               const float* __restrict__ bias,
                                               const float* __restrict__ gam,
                                               const float* __restrict__ bet,
                                               const float* __restrict__ mu,
                                               const float* __restrict__ var,
                                               ushort* __restrict__ out, int n) {
    int wave = threadIdx.x >> 6, lane = threadIdx.x & 63;
    int vtx = blockIdx.x * 4 + wave;
    if (vtx >= n) return;
    int c0 = lane * 2;
    int beg = row_ptr[vtx], end = row_ptr[vtx + 1];
    float a0 = 0.f, a1 = 0.f;
    int e = beg;
    for (; e + 1 < end; e += 2) {
        int s0 = csr_src[e], s1 = csr_src[e + 1];
        float w0 = dinv[s0], w1 = dinv[s1];
        unsigned u0 = *reinterpret_cast<const unsigned*>(h + (size_t)s0 * 128 + c0);
        unsigned u1 = *reinterpret_cast<const unsigned*>(h + (size_t)s1 * 128 + c0);
        a0 = fmaf(bflo(u0), w0, a0); a1 = fmaf(bfhi(u0), w0, a1);
        a0 = fmaf(bflo(u1), w1, a0); a1 = fmaf(bfhi(u1), w1, a1);
    }
    if (e < end) {
        int s0 = csr_src[e];
        float w0 = dinv[s0];
        unsigned u0 = *reinterpret_cast<const unsigned*>(h + (size_t)s0 * 128 + c0);
        a0 = fmaf(bflo(u0), w0, a0); a1 = fmaf(bfhi(u0), w0, a1);
    }
    float dv = dinv[vtx];
    unsigned us = *reinterpret_cast<const unsigned*>(h + (size_t)vtx * 128 + c0);
    float v0 = a0 * dv + bflo(us) * dv * dv + bias[c0];
    float v1 = a1 * dv + bfhi(us) * dv * dv + bias[c0 + 1];
    float sc0 = gam[c0] * rsqrtf(var[c0] + BN_EPS);
    float sc1 = gam[c0 + 1] * rsqrtf(var[c0 + 1] + BN_EPS);
    v0 = fmaxf((v0 - mu[c0]) * sc0 + bet[c0], 0.f);
    v1 = fmaxf((v1 - mu[c0 + 1]) * sc1 + bet[c0 + 1], 0.f);
    unsigned packed = (unsigned)f2bf(v0) | ((unsigned)f2bf(v1) << 16);
    *reinterpret_cast<unsigned*>(out + (size_t)vtx * 128 + c0) = packed;
}

// ---------------- pooling ----------------
// counts via binary search on sorted batch (no atomics): counts[g] = lb(g+1) - lb(g)
__global__ void k_cnt2(const int* __restrict__ batch, float* __restrict__ counts, int n) {
    int g = threadIdx.x;  // one block of 256
    int lo = 0, hi = n;
    while (lo < hi) { int mid = (lo + hi) >> 1; if (batch[mid] < g) lo = mid + 1; else hi = mid; }
    int a = lo;
    lo = 0; hi = n;
    int g1 = g + 1;
    while (lo < hi) { int mid = (lo + hi) >> 1; if (batch[mid] < g1) lo = mid + 1; else hi = mid; }
    counts[g] = (float)(lo - a);
}

// 64 nodes per block, lane handles 2 channels; run-length accumulate (batch sorted)
__global__ __launch_bounds__(64) void k_pool(const ushort* __restrict__ h,
                                             const int* __restrict__ batch,
                                             float* __restrict__ pooled, int n) {
    int lane = threadIdx.x;
    int c0 = lane * 2;
    int n0 = blockIdx.x * 64;
    if (n0 >= n) return;
    int n1 = min(n0 + 64, n);
    float a0 = 0.f, a1 = 0.f;
    int cur = batch[n0];
    for (int i = n0; i < n1; ++i) {
        int g = batch[i];
        if (g != cur) {
            atomicAdd(&pooled[cur * 128 + c0], a0);
            atomicAdd(&pooled[cur * 128 + c0 + 1], a1);
            a0 = 0.f; a1 = 0.f;
            cur = g;
        }
        unsigned u = *reinterpret_cast<const unsigned*>(h + (size_t)i * 128 + c0);
        a0 += bflo(u); a1 += bfhi(u);
    }
    atomicAdd(&pooled[cur * 128 + c0], a0);
    atomicAdd(&pooled[cur * 128 + c0 + 1], a1);
}

__global__ void k_final(const float* __restrict__ pooled, const float* __restrict__ counts,
                        const float* __restrict__ lw, const float* __restrict__ lb,
                        float* __restrict__ out) {
    int t = blockIdx.x * blockDim.x + threadIdx.x;
    if (t >= N_GRAPHS * N_CLASSES) return;
    int g = t / N_CLASSES, cls = t % N_CLASSES;
    float inv = 1.0f / fmaxf(counts[g], 1.0f);
    float acc = 0.f;
    for (int k = 0; k < 128; ++k)
        acc += pooled[g * 128 + k] * lw[k * N_CLASSES + cls];
    out[t] = acc * inv + lb[cls];
}

// ---------------- launch ----------------
extern "C" void kernel_launch(void* const* d_in, const int* in_sizes, int n_in,
                              void* d_out, int out_size, void* d_ws, size_t ws_size,
                              hipStream_t stream) {
    const float* x      = (const float*)d_in[0];
    const int*   ei     = (const int*)d_in[1];
    const int*   batch  = (const int*)d_in[2];
    const float* W0  = (const float*)d_in[3];
    const float* b0  = (const float*)d_in[4];
    const float* g0  = (const float*)d_in[5];
    const float* bt0 = (const float*)d_in[6];
    const float* m0  = (const float*)d_in[7];
    const float* v0  = (const float*)d_in[8];
    const float* W1  = (const float*)d_in[9];
    const float* b1  = (const float*)d_in[10];
    const float* g1  = (const float*)d_in[11];
    const float* bt1 = (const float*)d_in[12];
    const float* m1  = (const float*)d_in[13];
    const float* v1  = (const float*)d_in[14];
    const float* W2  = (const float*)d_in[15];
    const float* b2  = (const float*)d_in[16];
    const float* g2  = (const float*)d_in[17];
    const float* bt2 = (const float*)d_in[18];
    const float* m2  = (const float*)d_in[19];
    const float* v2  = (const float*)d_in[20];
    const float* lw  = (const float*)d_in[21];
    const float* lb  = (const float*)d_in[22];
    float* out = (float*)d_out;

    const int N = in_sizes[2];          // 50000
    const int E = in_sizes[1] / 2;      // 800000
    const int* row = ei;
    const int* col = ei + E;

    char* ws = (char*)d_ws;
    size_t off = 0;
    auto alloc = [&](size_t bytes) {
        void* p = ws + off;
        off += (bytes + 511) & ~(size_t)511;
        return p;
    };
    ushort* hA     = (ushort*)alloc((size_t)N * 128 * 2);   // bf16 activations
    ushort* hB     = (ushort*)alloc((size_t)N * 128 * 2);
    ushort* Wt0    = (ushort*)alloc((size_t)128 * IN_C * 2);
    ushort* Wt1    = (ushort*)alloc((size_t)128 * HID_C * 2);
    ushort* Wt2    = (ushort*)alloc((size_t)128 * HID_C * 2);
    int*   ecnt    = (int*)alloc((size_t)N * 4);
    int*   cursor  = (int*)alloc((size_t)N * 4);
    int*   row_ptr = (int*)alloc((size_t)(N + 1) * 4);
    int*   csr_src = (int*)alloc((size_t)E * 4);
    float* dinv    = (float*)alloc((size_t)N * 4);
    int*   bsum    = (int*)alloc(256 * 4);
    int*   bsumx   = (int*)alloc(256 * 4);
    float* pooled  = (float*)alloc((size_t)N_GRAPHS * 128 * 4);
    float* counts  = (float*)alloc((size_t)N_GRAPHS * 4);

    const int NB_n = (N + 255) / 256;   // 196
    const int NB_e = (E + 255) / 256;   // 3125

    k_init<<<NB_n, 256, 0, stream>>>(ecnt, cursor, pooled, N);
    k_count<<<NB_e, 256, 0, stream>>>(col, ecnt, E);
    k_dinv<<<NB_n, 256, 0, stream>>>(ecnt, dinv, N);
    k_scanA<<<NB_n, 256, 0, stream>>>(ecnt, row_ptr, bsum, N);
    k_scanB<<<1, 256, 0, stream>>>(bsum, bsumx, NB_n);
    k_scanC<<<NB_n, 256, 0, stream>>>(ecnt, row_ptr, bsumx, N, E);
    k_fill<<<NB_e, 256, 0, stream>>>(row, col, row_ptr, cursor, csr_src, E);

    k_prepW<<<(128 * IN_C + 255) / 256, 256, 0, stream>>>(W0, Wt0, IN_C);
    k_prepW<<<(128 * HID_C + 255) / 256, 256, 0, stream>>>(W1, Wt1, HID_C);
    k_prepW<<<(128 * HID_C + 255) / 256, 256, 0, stream>>>(W2, Wt2, HID_C);

    const int GB = (N + 63) / 64;       // 782
    const int AB = (N + 3) / 4;         // 12500

    // layer 0: x fp32 (K=256) -> hB bf16 -> hA bf16
    k_gemmbf<IN_C, true><<<GB, 256, IN_C * 128 * 2, stream>>>(x, Wt0, hB, N);
    k_aggbf<<<AB, 256, 0, stream>>>(hB, row_ptr, csr_src, dinv, b0, g0, bt0, m0, v0, hA, N);
    // layer 1
    k_gemmbf<HID_C, false><<<GB, 256, HID_C * 128 * 2, stream>>>(hA, Wt1, hB, N);
    k_aggbf<<<AB, 256, 0, stream>>>(hB, row_ptr, csr_src, dinv, b1, g1, bt1, m1, v1, hA, N);
    // layer 2
    k_gemmbf<HID_C, false><<<GB, 256, HID_C * 128 * 2, stream>>>(hA, Wt2, hB, N);
    k_aggbf<<<AB, 256, 0, stream>>>(hB, row_ptr, csr_src, dinv, b2, g2, bt2, m2, v2, hA, N);

    // pooling + classifier
    k_cnt2<<<1, 256, 0, stream>>>(batch, counts, N);
    k_pool<<<(N + 63) / 64, 64, 0, stream>>>(hA, batch, pooled, N);
    k_final<<<(N_GRAPHS * N_CLASSES + 255) / 256, 256, 0, stream>>>(pooled, counts, lw, lb, out);
}

// Round 4
// 296.826 us; speedup vs baseline: 1.9880x; 1.1817x over previous
//
#include <hip/hip_runtime.h>
#include <hip/hip_bf16.h>

// ---------------- problem constants ----------------
#define N_NODES   50000
#define N_EDGES   800000
#define IN_C      256
#define HID_C     128
#define N_GRAPHS  256
#define N_CLASSES 6
#define BN_EPS    1e-5f

using bf16x8 = __attribute__((ext_vector_type(8))) short;
using f32x4  = __attribute__((ext_vector_type(4))) float;

__device__ __forceinline__ ushort f2bf(float f) {
    union { float f; unsigned u; } v; v.f = f;
    unsigned r = v.u + 0x7fffu + ((v.u >> 16) & 1u);
    return (ushort)(r >> 16);
}
__device__ __forceinline__ float bflo(unsigned u) {
    union { unsigned u; float f; } v; v.u = u << 16; return v.f;
}
__device__ __forceinline__ float bfhi(unsigned u) {
    union { unsigned u; float f; } v; v.u = u & 0xffff0000u; return v.f;
}

// ---------------- CSR build ----------------
__global__ void k_init(int* ecnt, int* cursor, float* pooled, int n) {
    int i = blockIdx.x * blockDim.x + threadIdx.x;
    if (i < n) { ecnt[i] = 0; cursor[i] = 0; }
    if (i < N_GRAPHS * HID_C) pooled[i] = 0.f;
}

__global__ void k_count(const int* __restrict__ col, int* __restrict__ ecnt, int e) {
    int i = blockIdx.x * blockDim.x + threadIdx.x;
    if (i < e) atomicAdd(&ecnt[col[i]], 1);
}

__global__ void k_dinv(const int* __restrict__ ecnt, float* __restrict__ dinv, int n) {
    int i = blockIdx.x * blockDim.x + threadIdx.x;
    if (i < n) dinv[i] = rsqrtf((float)(ecnt[i] + 1));  // +1 self loop
}

__global__ void k_scanA(const int* __restrict__ ecnt, int* __restrict__ row_ptr,
                        int* __restrict__ bsum, int n) {
    __shared__ int s[256];
    int t = threadIdx.x;
    int i = blockIdx.x * 256 + t;
    int v = (i < n) ? ecnt[i] : 0;
    s[t] = v;
    __syncthreads();
    for (int d = 1; d < 256; d <<= 1) {
        int add = (t >= d) ? s[t - d] : 0;
        __syncthreads();
        s[t] += add;
        __syncthreads();
    }
    if (i < n) row_ptr[i] = s[t];
    if (t == 255) bsum[blockIdx.x] = s[255];
}

__global__ void k_scanB(const int* __restrict__ bsum, int* __restrict__ bsumx, int nb) {
    __shared__ int s[256];
    int t = threadIdx.x;
    int v = (t < nb) ? bsum[t] : 0;
    s[t] = v;
    __syncthreads();
    for (int d = 1; d < 256; d <<= 1) {
        int add = (t >= d) ? s[t - d] : 0;
        __syncthreads();
        s[t] += add;
        __syncthreads();
    }
    bsumx[t] = s[t] - v;
}

__global__ void k_scanC(const int* __restrict__ ecnt, int* __restrict__ row_ptr,
                        const int* __restrict__ bsumx, int n, int e) {
    int i = blockIdx.x * 256 + threadIdx.x;
    if (i < n) row_ptr[i] = row_ptr[i] - ecnt[i] + bsumx[blockIdx.x];
    if (i == 0) row_ptr[n] = e;
}

__global__ void k_fill(const int* __restrict__ row, const int* __restrict__ col,
                       const int* __restrict__ row_ptr, int* __restrict__ cursor,
                       int* __restrict__ csr_src, int e) {
    int i = blockIdx.x * blockDim.x + threadIdx.x;
    if (i < e) {
        int c = col[i];
        int pos = row_ptr[c] + atomicAdd(&cursor[c], 1);
        csr_src[pos] = row[i];
    }
}

// ---------------- weight prep: cast + transpose  Wt[co][k] = bf16(W[k][co]) ----------------
__global__ void k_prepW(const float* __restrict__ W, ushort* __restrict__ Wt, int K) {
    int t = blockIdx.x * blockDim.x + threadIdx.x;
    if (t >= 128 * K) return;
    int co = t / K, k = t % K;
    Wt[t] = f2bf(W[(size_t)k * 128 + co]);
}

// ---------------- MFMA GEMM: Cbf[M,128] = A[M,K] @ W[K,128]  (bf16 in, bf16 out) ----------
// block = 256 threads = 4 waves; each wave does 16 rows x 128 cols; K fully in LDS (swizzled)
template <int K, bool AFP32>
__global__ __launch_bounds__(256) void k_gemmbf(const void* __restrict__ Av,
                                                const ushort* __restrict__ Wt,
                                                ushort* __restrict__ Cbf, int M) {
    extern __shared__ char smem[];  // K*128*2 bytes, layout: [col][k] bf16, 16B-XOR swizzled
    const int tid = threadIdx.x;
    constexpr int CPC = K / 8;          // 16B chunks per col
    constexpr int NCH = 128 * CPC;
    for (int c = tid; c < NCH; c += 256) {
        int col = c / CPC, kg = c % CPC;
        float4 v = *reinterpret_cast<const float4*>(Wt + (size_t)col * K + kg * 8);
        int dst = col * (K * 2) + ((kg * 16) ^ ((col & 7) << 4));
        *reinterpret_cast<float4*>(smem + dst) = v;
    }
    __syncthreads();

    const int wave = tid >> 6, lane = tid & 63;
    const int l15 = lane & 15, lg = lane >> 4;
    const int row = blockIdx.x * 64 + wave * 16 + l15;
    const bool rok = (row < M);

    f32x4 acc[8] = {};

#pragma unroll
    for (int ks = 0; ks < K / 32; ++ks) {
        bf16x8 a;
        if (AFP32) {
            const float* Ap = (const float*)Av + (size_t)row * K + ks * 32 + lg * 8;
            float4 f0, f1;
            if (rok) {
                f0 = *reinterpret_cast<const float4*>(Ap);
                f1 = *reinterpret_cast<const float4*>(Ap + 4);
            } else {
                f0 = make_float4(0, 0, 0, 0); f1 = f0;
            }
            a[0] = (short)f2bf(f0.x); a[1] = (short)f2bf(f0.y);
            a[2] = (short)f2bf(f0.z); a[3] = (short)f2bf(f0.w);
            a[4] = (short)f2bf(f1.x); a[5] = (short)f2bf(f1.y);
            a[6] = (short)f2bf(f1.z); a[7] = (short)f2bf(f1.w);
        } else {
            if (rok) {
                const ushort* Ap = (const ushort*)Av + (size_t)row * K + ks * 32 + lg * 8;
                a = *reinterpret_cast<const bf16x8*>(Ap);
            } else {
#pragma unroll
                for (int j = 0; j < 8; ++j) a[j] = 0;
            }
        }
#pragma unroll
        for (int cf = 0; cf < 8; ++cf) {
            int col = cf * 16 + l15;
            int off = col * (K * 2) + ((ks * 64 + lg * 16) ^ ((col & 7) << 4));
            bf16x8 b = *reinterpret_cast<const bf16x8*>(smem + off);
            acc[cf] = __builtin_amdgcn_mfma_f32_16x16x32_bf16(a, b, acc[cf], 0, 0, 0);
        }
    }

    // C/D layout: col = lane&15, row = (lane>>4)*4 + i   [m89-verified]
#pragma unroll
    for (int cf = 0; cf < 8; ++cf) {
        int col = cf * 16 + l15;
#pragma unroll
        for (int i = 0; i < 4; ++i) {
            int r = blockIdx.x * 64 + wave * 16 + lg * 4 + i;
            if (r < M) Cbf[(size_t)r * 128 + col] = f2bf(acc[cf][i]);
        }
    }
}

// ---------------- aggregate + bias + BN + ReLU  (bf16 h -> bf16 out) ----------------
// 4 waves/block, one node per wave. Half-wave split: lanes 0-31 take even edge
// slots, 32-63 odd; each lane covers 4 channels (32 lanes x 8B = full 256B row
// per half-wave => one dwordx2 instruction fetches TWO rows). Edge indices and
// dinv weights are preloaded into lanes and broadcast via __shfl (no dependent
// memory chain). Halves merged with __shfl_xor(.,32) at the end.
__global__ __launch_bounds__(256) void k_aggbf(const ushort* __restrict__ h,
                                               const int* __restrict__ row_ptr,
                                               const int* __restrict__ csr_src,
                                               const float* __restrict__ dinv,
                                               const float* __restrict__ bias,
                                               const float* __restrict__ gam,
                                               const float* __restrict__ bet,
                                               const float* __restrict__ mu,
                                               const float* __restrict__ var,
                                               ushort* __restrict__ out, int n) {
    int wave = threadIdx.x >> 6, lane = threadIdx.x & 63;
    int vtx = blockIdx.x * 4 + wave;
    if (vtx >= n) return;
    int l31 = lane & 31, half = lane >> 5;
    int c0 = l31 * 4;  // 4 channels per lane
    int beg = row_ptr[vtx], end = row_ptr[vtx + 1];
    int deg = end - beg;
    int npre = min(deg, 64);

    // preload edge index + weight into lane l
    int   pidx = 0;
    float pw   = 0.f;
    if (lane < npre) { pidx = csr_src[beg + lane]; pw = dinv[pidx]; }

    float a0 = 0.f, a1 = 0.f, a2 = 0.f, a3 = 0.f;
    int j = 0;
    // 4 edges per iteration: each half-wave handles 2
    for (; j + 3 < npre; j += 4) {
        int   sA = __shfl(pidx, j + half);
        float wA = __shfl(pw,   j + half);
        int   sB = __shfl(pidx, j + 2 + half);
        float wB = __shfl(pw,   j + 2 + half);
        uint2 uA = *reinterpret_cast<const uint2*>(h + (size_t)sA * 128 + c0);
        uint2 uB = *reinterpret_cast<const uint2*>(h + (size_t)sB * 128 + c0);
        a0 = fmaf(bflo(uA.x), wA, a0); a1 = fmaf(bfhi(uA.x), wA, a1);
        a2 = fmaf(bflo(uA.y), wA, a2); a3 = fmaf(bfhi(uA.y), wA, a3);
        a0 = fmaf(bflo(uB.x), wB, a0); a1 = fmaf(bfhi(uB.x), wB, a1);
        a2 = fmaf(bflo(uB.y), wB, a2); a3 = fmaf(bfhi(uB.y), wB, a3);
    }
    // 2 edges
    if (j + 1 < npre) {
        int   s = __shfl(pidx, j + half);
        float w = __shfl(pw,   j + half);
        uint2 u = *reinterpret_cast<const uint2*>(h + (size_t)s * 128 + c0);
        a0 = fmaf(bflo(u.x), w, a0); a1 = fmaf(bfhi(u.x), w, a1);
        a2 = fmaf(bflo(u.y), w, a2); a3 = fmaf(bfhi(u.y), w, a3);
        j += 2;
    }
    // 1 leftover edge: only half 0 accumulates (half 1 would double-count after merge)
    if (j < npre) {
        int   s = __shfl(pidx, j);
        float w = __shfl(pw, j) * (half ? 0.f : 1.f);
        uint2 u = *reinterpret_cast<const uint2*>(h + (size_t)s * 128 + c0);
        a0 = fmaf(bflo(u.x), w, a0); a1 = fmaf(bfhi(u.x), w, a1);
        a2 = fmaf(bflo(u.y), w, a2); a3 = fmaf(bfhi(u.y), w, a3);
    }
    // rare tail: deg > 64, half-wave strided serial
    for (int e = beg + 64 + half; e < end; e += 2) {
        int   s = csr_src[e];
        float w = dinv[s];
        uint2 u = *reinterpret_cast<const uint2*>(h + (size_t)s * 128 + c0);
        a0 = fmaf(bflo(u.x), w, a0); a1 = fmaf(bfhi(u.x), w, a1);
        a2 = fmaf(bflo(u.y), w, a2); a3 = fmaf(bfhi(u.y), w, a3);
    }

    // merge half-wave partials
    a0 += __shfl_xor(a0, 32);
    a1 += __shfl_xor(a1, 32);
    a2 += __shfl_xor(a2, 32);
    a3 += __shfl_xor(a3, 32);

    float dv = dinv[vtx];
    uint2 us = *reinterpret_cast<const uint2*>(h + (size_t)vtx * 128 + c0);
    float4 bi = *reinterpret_cast<const float4*>(bias + c0);
    float4 gm = *reinterpret_cast<const float4*>(gam + c0);
    float4 bt = *reinterpret_cast<const float4*>(bet + c0);
    float4 muv = *reinterpret_cast<const float4*>(mu + c0);
    float4 vr = *reinterpret_cast<const float4*>(var + c0);
    float dvv = dv * dv;
    float v0 = a0 * dv + bflo(us.x) * dvv + bi.x;
    float v1 = a1 * dv + bfhi(us.x) * dvv + bi.y;
    float v2 = a2 * dv + bflo(us.y) * dvv + bi.z;
    float v3 = a3 * dv + bfhi(us.y) * dvv + bi.w;
    v0 = fmaxf((v0 - muv.x) * (gm.x * rsqrtf(vr.x + BN_EPS)) + bt.x, 0.f);
    v1 = fmaxf((v1 - muv.y) * (gm.y * rsqrtf(vr.y + BN_EPS)) + bt.y, 0.f);
    v2 = fmaxf((v2 - muv.z) * (gm.z * rsqrtf(vr.z + BN_EPS)) + bt.z, 0.f);
    v3 = fmaxf((v3 - muv.w) * (gm.w * rsqrtf(vr.w + BN_EPS)) + bt.w, 0.f);
    if (half == 0) {
        uint2 packed;
        packed.x = (unsigned)f2bf(v0) | ((unsigned)f2bf(v1) << 16);
        packed.y = (unsigned)f2bf(v2) | ((unsigned)f2bf(v3) << 16);
        *reinterpret_cast<uint2*>(out + (size_t)vtx * 128 + c0) = packed;
    }
}

// ---------------- pooling ----------------
// counts via binary search on sorted batch (no atomics): counts[g] = lb(g+1) - lb(g)
__global__ void k_cnt2(const int* __restrict__ batch, float* __restrict__ counts, int n) {
    int g = threadIdx.x;  // one block of 256
    int lo = 0, hi = n;
    while (lo < hi) { int mid = (lo + hi) >> 1; if (batch[mid] < g) lo = mid + 1; else hi = mid; }
    int a = lo;
    lo = 0; hi = n;
    int g1 = g + 1;
    while (lo < hi) { int mid = (lo + hi) >> 1; if (batch[mid] < g1) lo = mid + 1; else hi = mid; }
    counts[g] = (float)(lo - a);
}

// 64 nodes per block, lane handles 2 channels; run-length accumulate (batch sorted)
__global__ __launch_bounds__(64) void k_pool(const ushort* __restrict__ h,
                                             const int* __restrict__ batch,
                                             float* __restrict__ pooled, int n) {
    int lane = threadIdx.x;
    int c0 = lane * 2;
    int n0 = blockIdx.x * 64;
    if (n0 >= n) return;
    int n1 = min(n0 + 64, n);
    float a0 = 0.f, a1 = 0.f;
    int cur = batch[n0];
    for (int i = n0; i < n1; ++i) {
        int g = batch[i];
        if (g != cur) {
            atomicAdd(&pooled[cur * 128 + c0], a0);
            atomicAdd(&pooled[cur * 128 + c0 + 1], a1);
            a0 = 0.f; a1 = 0.f;
            cur = g;
        }
        unsigned u = *reinterpret_cast<const unsigned*>(h + (size_t)i * 128 + c0);
        a0 += bflo(u); a1 += bfhi(u);
    }
    atomicAdd(&pooled[cur * 128 + c0], a0);
    atomicAdd(&pooled[cur * 128 + c0 + 1], a1);
}

__global__ void k_final(const float* __restrict__ pooled, const float* __restrict__ counts,
                        const float* __restrict__ lw, const float* __restrict__ lb,
                        float* __restrict__ out) {
    int t = blockIdx.x * blockDim.x + threadIdx.x;
    if (t >= N_GRAPHS * N_CLASSES) return;
    int g = t / N_CLASSES, cls = t % N_CLASSES;
    float inv = 1.0f / fmaxf(counts[g], 1.0f);
    float acc = 0.f;
    for (int k = 0; k < 128; ++k)
        acc += pooled[g * 128 + k] * lw[k * N_CLASSES + cls];
    out[t] = acc * inv + lb[cls];
}

// ---------------- launch ----------------
extern "C" void kernel_launch(void* const* d_in, const int* in_sizes, int n_in,
                              void* d_out, int out_size, void* d_ws, size_t ws_size,
                              hipStream_t stream) {
    const float* x      = (const float*)d_in[0];
    const int*   ei     = (const int*)d_in[1];
    const int*   batch  = (const int*)d_in[2];
    const float* W0  = (const float*)d_in[3];
    const float* b0  = (const float*)d_in[4];
    const float* g0  = (const float*)d_in[5];
    const float* bt0 = (const float*)d_in[6];
    const float* m0  = (const float*)d_in[7];
    const float* v0  = (const float*)d_in[8];
    const float* W1  = (const float*)d_in[9];
    const float* b1  = (const float*)d_in[10];
    const float* g1  = (const float*)d_in[11];
    const float* bt1 = (const float*)d_in[12];
    const float* m1  = (const float*)d_in[13];
    const float* v1  = (const float*)d_in[14];
    const float* W2  = (const float*)d_in[15];
    const float* b2  = (const float*)d_in[16];
    const float* g2  = (const float*)d_in[17];
    const float* bt2 = (const float*)d_in[18];
    const float* m2  = (const float*)d_in[19];
    const float* v2  = (const float*)d_in[20];
    const float* lw  = (const float*)d_in[21];
    const float* lb  = (const float*)d_in[22];
    float* out = (float*)d_out;

    const int N = in_sizes[2];          // 50000
    const int E = in_sizes[1] / 2;      // 800000
    const int* row = ei;
    const int* col = ei + E;

    char* ws = (char*)d_ws;
    size_t off = 0;
    auto alloc = [&](size_t bytes) {
        void* p = ws + off;
        off += (bytes + 511) & ~(size_t)511;
        return p;
    };
    ushort* hA     = (ushort*)alloc((size_t)N * 128 * 2);   // bf16 activations
    ushort* hB     = (ushort*)alloc((size_t)N * 128 * 2);
    ushort* Wt0    = (ushort*)alloc((size_t)128 * IN_C * 2);
    ushort* Wt1    = (ushort*)alloc((size_t)128 * HID_C * 2);
    ushort* Wt2    = (ushort*)alloc((size_t)128 * HID_C * 2);
    int*   ecnt    = (int*)alloc((size_t)N * 4);
    int*   cursor  = (int*)alloc((size_t)N * 4);
    int*   row_ptr = (int*)alloc((size_t)(N + 1) * 4);
    int*   csr_src = (int*)alloc((size_t)E * 4);
    float* dinv    = (float*)alloc((size_t)N * 4);
    int*   bsum    = (int*)alloc(256 * 4);
    int*   bsumx   = (int*)alloc(256 * 4);
    float* pooled  = (float*)alloc((size_t)N_GRAPHS * 128 * 4);
    float* counts  = (float*)alloc((size_t)N_GRAPHS * 4);

    const int NB_n = (N + 255) / 256;   // 196
    const int NB_e = (E + 255) / 256;   // 3125

    k_init<<<NB_n, 256, 0, stream>>>(ecnt, cursor, pooled, N);
    k_count<<<NB_e, 256, 0, stream>>>(col, ecnt, E);
    k_dinv<<<NB_n, 256, 0, stream>>>(ecnt, dinv, N);
    k_scanA<<<NB_n, 256, 0, stream>>>(ecnt, row_ptr, bsum, N);
    k_scanB<<<1, 256, 0, stream>>>(bsum, bsumx, NB_n);
    k_scanC<<<NB_n, 256, 0, stream>>>(ecnt, row_ptr, bsumx, N, E);
    k_fill<<<NB_e, 256, 0, stream>>>(row, col, row_ptr, cursor, csr_src, E);

    k_prepW<<<(128 * IN_C + 255) / 256, 256, 0, stream>>>(W0, Wt0, IN_C);
    k_prepW<<<(128 * HID_C + 255) / 256, 256, 0, stream>>>(W1, Wt1, HID_C);
    k_prepW<<<(128 * HID_C + 255) / 256, 256, 0, stream>>>(W2, Wt2, HID_C);

    const int GB = (N + 63) / 64;       // 782
    const int AB = (N + 3) / 4;         // 12500

    // layer 0: x fp32 (K=256) -> hB bf16 -> hA bf16
    k_gemmbf<IN_C, true><<<GB, 256, IN_C * 128 * 2, stream>>>(x, Wt0, hB, N);
    k_aggbf<<<AB, 256, 0, stream>>>(hB, row_ptr, csr_src, dinv, b0, g0, bt0, m0, v0, hA, N);
    // layer 1
    k_gemmbf<HID_C, false><<<GB, 256, HID_C * 128 * 2, stream>>>(hA, Wt1, hB, N);
    k_aggbf<<<AB, 256, 0, stream>>>(hB, row_ptr, csr_src, dinv, b1, g1, bt1, m1, v1, hA, N);
    // layer 2
    k_gemmbf<HID_C, false><<<GB, 256, HID_C * 128 * 2, stream>>>(hA, Wt2, hB, N);
    k_aggbf<<<AB, 256, 0, stream>>>(hB, row_ptr, csr_src, dinv, b2, g2, bt2, m2, v2, hA, N);

    // pooling + classifier
    k_cnt2<<<1, 256, 0, stream>>>(batch, counts, N);
    k_pool<<<(N + 63) / 64, 64, 0, stream>>>(hA, batch, pooled, N);
    k_final<<<(N_GRAPHS * N_CLASSES + 255) / 256, 256, 0, stream>>>(pooled, counts, lw, lb, out);
}

// Round 5
// 267.138 us; speedup vs baseline: 2.2089x; 1.1111x over previous
//
#include <hip/hip_runtime.h>
#include <hip/hip_bf16.h>

// ---------------- problem constants ----------------
#define N_NODES   50000
#define N_EDGES   800000
#define IN_C      256
#define HID_C     128
#define N_GRAPHS  256
#define N_CLASSES 6
#define BN_EPS    1e-5f

using bf16x8 = __attribute__((ext_vector_type(8))) short;
using f32x4  = __attribute__((ext_vector_type(4))) float;

__device__ __forceinline__ ushort f2bf(float f) {
    union { float f; unsigned u; } v; v.f = f;
    unsigned r = v.u + 0x7fffu + ((v.u >> 16) & 1u);
    return (ushort)(r >> 16);
}
__device__ __forceinline__ float bflo(unsigned u) {
    union { unsigned u; float f; } v; v.u = u << 16; return v.f;
}
__device__ __forceinline__ float bfhi(unsigned u) {
    union { unsigned u; float f; } v; v.u = u & 0xffff0000u; return v.f;
}

// ---------------- CSR build ----------------
__global__ void k_init(int* ecnt, float* pooled, int n) {
    int i = blockIdx.x * blockDim.x + threadIdx.x;
    if (i < n) ecnt[i] = 0;
    if (i < N_GRAPHS * HID_C) pooled[i] = 0.f;
}

// count + rank in one atomic pass: rank[i] = old count of col[i]
__global__ void k_count_rank(const int* __restrict__ col, int* __restrict__ ecnt,
                             int* __restrict__ rank, int e) {
    int i0 = (blockIdx.x * blockDim.x + threadIdx.x) * 4;
    if (i0 + 3 < e) {
        int4 c = *reinterpret_cast<const int4*>(col + i0);
        int4 r;
        r.x = atomicAdd(&ecnt[c.x], 1);
        r.y = atomicAdd(&ecnt[c.y], 1);
        r.z = atomicAdd(&ecnt[c.z], 1);
        r.w = atomicAdd(&ecnt[c.w], 1);
        *reinterpret_cast<int4*>(rank + i0) = r;
    } else {
        for (int i = i0; i < e; ++i) rank[i] = atomicAdd(&ecnt[col[i]], 1);
    }
}

// scan part A + dinv fused
__global__ void k_scanA(const int* __restrict__ ecnt, int* __restrict__ row_ptr,
                        int* __restrict__ bsum, float* __restrict__ dinv, int n) {
    __shared__ int s[256];
    int t = threadIdx.x;
    int i = blockIdx.x * 256 + t;
    int v = (i < n) ? ecnt[i] : 0;
    if (i < n) dinv[i] = rsqrtf((float)(v + 1));  // +1 self loop
    s[t] = v;
    __syncthreads();
    for (int d = 1; d < 256; d <<= 1) {
        int add = (t >= d) ? s[t - d] : 0;
        __syncthreads();
        s[t] += add;
        __syncthreads();
    }
    if (i < n) row_ptr[i] = s[t];
    if (t == 255) bsum[blockIdx.x] = s[255];
}

__global__ void k_scanB(const int* __restrict__ bsum, int* __restrict__ bsumx, int nb) {
    __shared__ int s[256];
    int t = threadIdx.x;
    int v = (t < nb) ? bsum[t] : 0;
    s[t] = v;
    __syncthreads();
    for (int d = 1; d < 256; d <<= 1) {
        int add = (t >= d) ? s[t - d] : 0;
        __syncthreads();
        s[t] += add;
        __syncthreads();
    }
    bsumx[t] = s[t] - v;
}

__global__ void k_scanC(const int* __restrict__ ecnt, int* __restrict__ row_ptr,
                        const int* __restrict__ bsumx, int n, int e) {
    int i = blockIdx.x * 256 + threadIdx.x;
    if (i < n) row_ptr[i] = row_ptr[i] - ecnt[i] + bsumx[blockIdx.x];
    if (i == 0) row_ptr[n] = e;
}

// atomic-free fill using precomputed ranks
__global__ void k_fill(const int* __restrict__ row, const int* __restrict__ col,
                       const int* __restrict__ row_ptr, const int* __restrict__ rank,
                       int* __restrict__ csr_src, int e) {
    int i0 = (blockIdx.x * blockDim.x + threadIdx.x) * 4;
    if (i0 + 3 < e) {
        int4 c  = *reinterpret_cast<const int4*>(col + i0);
        int4 r  = *reinterpret_cast<const int4*>(row + i0);
        int4 rk = *reinterpret_cast<const int4*>(rank + i0);
        int p0 = row_ptr[c.x] + rk.x;
        int p1 = row_ptr[c.y] + rk.y;
        int p2 = row_ptr[c.z] + rk.z;
        int p3 = row_ptr[c.w] + rk.w;
        csr_src[p0] = r.x;
        csr_src[p1] = r.y;
        csr_src[p2] = r.z;
        csr_src[p3] = r.w;
    } else {
        for (int i = i0; i < e; ++i) csr_src[row_ptr[col[i]] + rank[i]] = row[i];
    }
}

// ---------------- weight prep (all 3 layers, one launch) ----------------
// Wt0[co][k] k<256, Wt1[co][k], Wt2[co][k] k<128
__global__ void k_prepW(const float* __restrict__ W0, const float* __restrict__ W1,
                        const float* __restrict__ W2, ushort* __restrict__ Wt0,
                        ushort* __restrict__ Wt1, ushort* __restrict__ Wt2) {
    int t = blockIdx.x * blockDim.x + threadIdx.x;
    if (t < 128 * IN_C) {
        int co = t / IN_C, k = t % IN_C;
        Wt0[t] = f2bf(W0[(size_t)k * 128 + co]);
    } else if (t < 128 * IN_C + 128 * HID_C) {
        int u = t - 128 * IN_C;
        int co = u / HID_C, k = u % HID_C;
        Wt1[u] = f2bf(W1[(size_t)k * 128 + co]);
    } else if (t < 128 * IN_C + 2 * 128 * HID_C) {
        int u = t - 128 * IN_C - 128 * HID_C;
        int co = u / HID_C, k = u % HID_C;
        Wt2[u] = f2bf(W2[(size_t)k * 128 + co]);
    }
}

// ---------------- MFMA GEMM: Cbf[M,128] = A[M,K] @ W[K,128]  (bf16 in, bf16 out) ----------
template <int K, bool AFP32>
__global__ __launch_bounds__(256) void k_gemmbf(const void* __restrict__ Av,
                                                const ushort* __restrict__ Wt,
                                                ushort* __restrict__ Cbf, int M) {
    extern __shared__ char smem[];  // K*128*2 bytes, layout: [col][k] bf16, 16B-XOR swizzled
    const int tid = threadIdx.x;
    constexpr int CPC = K / 8;          // 16B chunks per col
    constexpr int NCH = 128 * CPC;
    for (int c = tid; c < NCH; c += 256) {
        int col = c / CPC, kg = c % CPC;
        float4 v = *reinterpret_cast<const float4*>(Wt + (size_t)col * K + kg * 8);
        int dst = col * (K * 2) + ((kg * 16) ^ ((col & 7) << 4));
        *reinterpret_cast<float4*>(smem + dst) = v;
    }
    __syncthreads();

    const int wave = tid >> 6, lane = tid & 63;
    const int l15 = lane & 15, lg = lane >> 4;
    const int row = blockIdx.x * 64 + wave * 16 + l15;
    const bool rok = (row < M);

    f32x4 acc[8] = {};

#pragma unroll
    for (int ks = 0; ks < K / 32; ++ks) {
        bf16x8 a;
        if (AFP32) {
            const float* Ap = (const float*)Av + (size_t)row * K + ks * 32 + lg * 8;
            float4 f0, f1;
            if (rok) {
                f0 = *reinterpret_cast<const float4*>(Ap);
                f1 = *reinterpret_cast<const float4*>(Ap + 4);
            } else {
                f0 = make_float4(0, 0, 0, 0); f1 = f0;
            }
            a[0] = (short)f2bf(f0.x); a[1] = (short)f2bf(f0.y);
            a[2] = (short)f2bf(f0.z); a[3] = (short)f2bf(f0.w);
            a[4] = (short)f2bf(f1.x); a[5] = (short)f2bf(f1.y);
            a[6] = (short)f2bf(f1.z); a[7] = (short)f2bf(f1.w);
        } else {
            if (rok) {
                const ushort* Ap = (const ushort*)Av + (size_t)row * K + ks * 32 + lg * 8;
                a = *reinterpret_cast<const bf16x8*>(Ap);
            } else {
#pragma unroll
                for (int j = 0; j < 8; ++j) a[j] = 0;
            }
        }
#pragma unroll
        for (int cf = 0; cf < 8; ++cf) {
            int col = cf * 16 + l15;
            int off = col * (K * 2) + ((ks * 64 + lg * 16) ^ ((col & 7) << 4));
            bf16x8 b = *reinterpret_cast<const bf16x8*>(smem + off);
            acc[cf] = __builtin_amdgcn_mfma_f32_16x16x32_bf16(a, b, acc[cf], 0, 0, 0);
        }
    }

    // C/D layout: col = lane&15, row = (lane>>4)*4 + i   [m89-verified]
#pragma unroll
    for (int cf = 0; cf < 8; ++cf) {
        int col = cf * 16 + l15;
#pragma unroll
        for (int i = 0; i < 4; ++i) {
            int r = blockIdx.x * 64 + wave * 16 + lg * 4 + i;
            if (r < M) Cbf[(size_t)r * 128 + col] = f2bf(acc[cf][i]);
        }
    }
}

// ---------------- aggregate + bias + BN + ReLU  (bf16 h -> bf16 out) ----------------
// 4 waves/block, one node per wave. Quarter-wave split: quarter q = lane>>4 takes
// edge slot j+q; each lane covers 8 channels via one dwordx4 (16 lanes x 16B =
// full 256B row per quarter => one load instruction fetches FOUR rows). Edge
// indices/weights preloaded into lanes, broadcast via __shfl; lanes >= npre
// carry w=0 so tail handling is branch-free. Quarters merged via shfl_xor 16,32.
__global__ __launch_bounds__(256) void k_aggbf(const ushort* __restrict__ h,
                                               const int* __restrict__ row_ptr,
                                               const int* __restrict__ csr_src,
                                               const float* __restrict__ dinv,
                                               const float* __restrict__ bias,
                                               const float* __restrict__ gam,
                                               const float* __restrict__ bet,
                                               const float* __restrict__ mu,
                                               const float* __restrict__ var,
                                               ushort* __restrict__ out, int n) {
    int wave = threadIdx.x >> 6, lane = threadIdx.x & 63;
    int vtx = blockIdx.x * 4 + wave;
    if (vtx >= n) return;
    int q = lane >> 4, l15 = lane & 15;
    int c0 = l15 * 8;  // 8 channels per lane
    int beg = row_ptr[vtx], end = row_ptr[vtx + 1];
    int deg = end - beg;
    int npre = min(deg, 64);

    // preload edge index + weight into lane l (lanes >= npre: w = 0)
    int   pidx = 0;
    float pw   = 0.f;
    if (lane < npre) { pidx = csr_src[beg + lane]; pw = dinv[pidx]; }

    float a0 = 0.f, a1 = 0.f, a2 = 0.f, a3 = 0.f;
    float a4 = 0.f, a5 = 0.f, a6 = 0.f, a7 = 0.f;
#pragma unroll 4
    for (int j = 0; j < npre; j += 4) {
        int   s = __shfl(pidx, j + q);
        float w = __shfl(pw,   j + q);
        uint4 u = *reinterpret_cast<const uint4*>(h + (size_t)s * 128 + c0);
        a0 = fmaf(bflo(u.x), w, a0); a1 = fmaf(bfhi(u.x), w, a1);
        a2 = fmaf(bflo(u.y), w, a2); a3 = fmaf(bfhi(u.y), w, a3);
        a4 = fmaf(bflo(u.z), w, a4); a5 = fmaf(bfhi(u.z), w, a5);
        a6 = fmaf(bflo(u.w), w, a6); a7 = fmaf(bfhi(u.w), w, a7);
    }
    // rare tail: deg > 64, quarter-strided serial
    for (int e = beg + 64 + q; e < end; e += 4) {
        int   s = csr_src[e];
        float w = dinv[s];
        uint4 u = *reinterpret_cast<const uint4*>(h + (size_t)s * 128 + c0);
        a0 = fmaf(bflo(u.x), w, a0); a1 = fmaf(bfhi(u.x), w, a1);
        a2 = fmaf(bflo(u.y), w, a2); a3 = fmaf(bfhi(u.y), w, a3);
        a4 = fmaf(bflo(u.z), w, a4); a5 = fmaf(bfhi(u.z), w, a5);
        a6 = fmaf(bflo(u.w), w, a6); a7 = fmaf(bfhi(u.w), w, a7);
    }

    // merge quarter partials
    a0 += __shfl_xor(a0, 16); a0 += __shfl_xor(a0, 32);
    a1 += __shfl_xor(a1, 16); a1 += __shfl_xor(a1, 32);
    a2 += __shfl_xor(a2, 16); a2 += __shfl_xor(a2, 32);
    a3 += __shfl_xor(a3, 16); a3 += __shfl_xor(a3, 32);
    a4 += __shfl_xor(a4, 16); a4 += __shfl_xor(a4, 32);
    a5 += __shfl_xor(a5, 16); a5 += __shfl_xor(a5, 32);
    a6 += __shfl_xor(a6, 16); a6 += __shfl_xor(a6, 32);
    a7 += __shfl_xor(a7, 16); a7 += __shfl_xor(a7, 32);

    float dv = dinv[vtx];
    float dvv = dv * dv;
    uint4 us = *reinterpret_cast<const uint4*>(h + (size_t)vtx * 128 + c0);
    float4 bi0 = *reinterpret_cast<const float4*>(bias + c0);
    float4 bi1 = *reinterpret_cast<const float4*>(bias + c0 + 4);
    float4 gm0 = *reinterpret_cast<const float4*>(gam + c0);
    float4 gm1 = *reinterpret_cast<const float4*>(gam + c0 + 4);
    float4 bt0v = *reinterpret_cast<const float4*>(bet + c0);
    float4 bt1v = *reinterpret_cast<const float4*>(bet + c0 + 4);
    float4 mu0 = *reinterpret_cast<const float4*>(mu + c0);
    float4 mu1 = *reinterpret_cast<const float4*>(mu + c0 + 4);
    float4 vr0 = *reinterpret_cast<const float4*>(var + c0);
    float4 vr1 = *reinterpret_cast<const float4*>(var + c0 + 4);

    float v0 = a0 * dv + bflo(us.x) * dvv + bi0.x;
    float v1 = a1 * dv + bfhi(us.x) * dvv + bi0.y;
    float v2 = a2 * dv + bflo(us.y) * dvv + bi0.z;
    float v3 = a3 * dv + bfhi(us.y) * dvv + bi0.w;
    float v4 = a4 * dv + bflo(us.z) * dvv + bi1.x;
    float v5 = a5 * dv + bfhi(us.z) * dvv + bi1.y;
    float v6 = a6 * dv + bflo(us.w) * dvv + bi1.z;
    float v7 = a7 * dv + bfhi(us.w) * dvv + bi1.w;
    v0 = fmaxf((v0 - mu0.x) * (gm0.x * rsqrtf(vr0.x + BN_EPS)) + bt0v.x, 0.f);
    v1 = fmaxf((v1 - mu0.y) * (gm0.y * rsqrtf(vr0.y + BN_EPS)) + bt0v.y, 0.f);
    v2 = fmaxf((v2 - mu0.z) * (gm0.z * rsqrtf(vr0.z + BN_EPS)) + bt0v.z, 0.f);
    v3 = fmaxf((v3 - mu0.w) * (gm0.w * rsqrtf(vr0.w + BN_EPS)) + bt0v.w, 0.f);
    v4 = fmaxf((v4 - mu1.x) * (gm1.x * rsqrtf(vr1.x + BN_EPS)) + bt1v.x, 0.f);
    v5 = fmaxf((v5 - mu1.y) * (gm1.y * rsqrtf(vr1.y + BN_EPS)) + bt1v.y, 0.f);
    v6 = fmaxf((v6 - mu1.z) * (gm1.z * rsqrtf(vr1.z + BN_EPS)) + bt1v.z, 0.f);
    v7 = fmaxf((v7 - mu1.w) * (gm1.w * rsqrtf(vr1.w + BN_EPS)) + bt1v.w, 0.f);
    if (q == 0) {
        uint4 packed;
        packed.x = (unsigned)f2bf(v0) | ((unsigned)f2bf(v1) << 16);
        packed.y = (unsigned)f2bf(v2) | ((unsigned)f2bf(v3) << 16);
        packed.z = (unsigned)f2bf(v4) | ((unsigned)f2bf(v5) << 16);
        packed.w = (unsigned)f2bf(v6) | ((unsigned)f2bf(v7) << 16);
        *reinterpret_cast<uint4*>(out + (size_t)vtx * 128 + c0) = packed;
    }
}

// ---------------- pooling ----------------
// 64 nodes per block, lane handles 2 channels; run-length accumulate (batch sorted)
__global__ __launch_bounds__(64) void k_pool(const ushort* __restrict__ h,
                                             const int* __restrict__ batch,
                                             float* __restrict__ pooled, int n) {
    int lane = threadIdx.x;
    int c0 = lane * 2;
    int n0 = blockIdx.x * 64;
    if (n0 >= n) return;
    int n1 = min(n0 + 64, n);
    float a0 = 0.f, a1 = 0.f;
    int cur = batch[n0];
    for (int i = n0; i < n1; ++i) {
        int g = batch[i];
        if (g != cur) {
            atomicAdd(&pooled[cur * 128 + c0], a0);
            atomicAdd(&pooled[cur * 128 + c0 + 1], a1);
            a0 = 0.f; a1 = 0.f;
            cur = g;
        }
        unsigned u = *reinterpret_cast<const unsigned*>(h + (size_t)i * 128 + c0);
        a0 += bflo(u); a1 += bfhi(u);
    }
    atomicAdd(&pooled[cur * 128 + c0], a0);
    atomicAdd(&pooled[cur * 128 + c0 + 1], a1);
}

// counts (binary search, sorted batch) + classifier, single block of 256
__global__ void k_final(const int* __restrict__ batch, const float* __restrict__ pooled,
                        const float* __restrict__ lw, const float* __restrict__ lb,
                        float* __restrict__ out, int n) {
    int g = threadIdx.x;  // one graph per thread
    int lo = 0, hi = n;
    while (lo < hi) { int mid = (lo + hi) >> 1; if (batch[mid] < g) lo = mid + 1; else hi = mid; }
    int a = lo;
    lo = 0; hi = n;
    int g1 = g + 1;
    while (lo < hi) { int mid = (lo + hi) >> 1; if (batch[mid] < g1) lo = mid + 1; else hi = mid; }
    float inv = 1.0f / fmaxf((float)(lo - a), 1.0f);
    float acc[N_CLASSES];
#pragma unroll
    for (int c = 0; c < N_CLASSES; ++c) acc[c] = 0.f;
    for (int k = 0; k < 128; ++k) {
        float p = pooled[g * 128 + k];
#pragma unroll
        for (int c = 0; c < N_CLASSES; ++c) acc[c] = fmaf(p, lw[k * N_CLASSES + c], acc[c]);
    }
#pragma unroll
    for (int c = 0; c < N_CLASSES; ++c) out[g * N_CLASSES + c] = acc[c] * inv + lb[c];
}

// ---------------- launch ----------------
extern "C" void kernel_launch(void* const* d_in, const int* in_sizes, int n_in,
                              void* d_out, int out_size, void* d_ws, size_t ws_size,
                              hipStream_t stream) {
    const float* x      = (const float*)d_in[0];
    const int*   ei     = (const int*)d_in[1];
    const int*   batch  = (const int*)d_in[2];
    const float* W0  = (const float*)d_in[3];
    const float* b0  = (const float*)d_in[4];
    const float* g0  = (const float*)d_in[5];
    const float* bt0 = (const float*)d_in[6];
    const float* m0  = (const float*)d_in[7];
    const float* v0  = (const float*)d_in[8];
    const float* W1  = (const float*)d_in[9];
    const float* b1  = (const float*)d_in[10];
    const float* g1  = (const float*)d_in[11];
    const float* bt1 = (const float*)d_in[12];
    const float* m1  = (const float*)d_in[13];
    const float* v1  = (const float*)d_in[14];
    const float* W2  = (const float*)d_in[15];
    const float* b2  = (const float*)d_in[16];
    const float* g2  = (const float*)d_in[17];
    const float* bt2 = (const float*)d_in[18];
    const float* m2  = (const float*)d_in[19];
    const float* v2  = (const float*)d_in[20];
    const float* lw  = (const float*)d_in[21];
    const float* lb  = (const float*)d_in[22];
    float* out = (float*)d_out;

    const int N = in_sizes[2];          // 50000
    const int E = in_sizes[1] / 2;      // 800000
    const int* row = ei;
    const int* col = ei + E;

    char* ws = (char*)d_ws;
    size_t off = 0;
    auto alloc = [&](size_t bytes) {
        void* p = ws + off;
        off += (bytes + 511) & ~(size_t)511;
        return p;
    };
    ushort* hA     = (ushort*)alloc((size_t)N * 128 * 2);   // bf16 activations
    ushort* hB     = (ushort*)alloc((size_t)N * 128 * 2);
    ushort* Wt0    = (ushort*)alloc((size_t)128 * IN_C * 2);
    ushort* Wt1    = (ushort*)alloc((size_t)128 * HID_C * 2);
    ushort* Wt2    = (ushort*)alloc((size_t)128 * HID_C * 2);
    int*   ecnt    = (int*)alloc((size_t)N * 4);
    int*   rank    = (int*)alloc((size_t)E * 4);
    int*   row_ptr = (int*)alloc((size_t)(N + 1) * 4);
    int*   csr_src = (int*)alloc((size_t)E * 4);
    float* dinv    = (float*)alloc((size_t)N * 4);
    int*   bsum    = (int*)alloc(256 * 4);
    int*   bsumx   = (int*)alloc(256 * 4);
    float* pooled  = (float*)alloc((size_t)N_GRAPHS * 128 * 4);

    const int NB_n  = (N + 255) / 256;        // 196
    const int NB_e4 = (E / 4 + 255) / 256;    // 782

    k_init<<<NB_n, 256, 0, stream>>>(ecnt, pooled, N);
    k_count_rank<<<NB_e4, 256, 0, stream>>>(col, ecnt, rank, E);
    k_scanA<<<NB_n, 256, 0, stream>>>(ecnt, row_ptr, bsum, dinv, N);
    k_scanB<<<1, 256, 0, stream>>>(bsum, bsumx, NB_n);
    k_scanC<<<NB_n, 256, 0, stream>>>(ecnt, row_ptr, bsumx, N, E);
    k_fill<<<NB_e4, 256, 0, stream>>>(row, col, row_ptr, rank, csr_src, E);

    k_prepW<<<(128 * (IN_C + 2 * HID_C) + 255) / 256, 256, 0, stream>>>(W0, W1, W2, Wt0, Wt1, Wt2);

    const int GB = (N + 63) / 64;       // 782
    const int AB = (N + 3) / 4;         // 12500

    // layer 0: x fp32 (K=256) -> hB bf16 -> hA bf16
    k_gemmbf<IN_C, true><<<GB, 256, IN_C * 128 * 2, stream>>>(x, Wt0, hB, N);
    k_aggbf<<<AB, 256, 0, stream>>>(hB, row_ptr, csr_src, dinv, b0, g0, bt0, m0, v0, hA, N);
    // layer 1
    k_gemmbf<HID_C, false><<<GB, 256, HID_C * 128 * 2, stream>>>(hA, Wt1, hB, N);
    k_aggbf<<<AB, 256, 0, stream>>>(hB, row_ptr, csr_src, dinv, b1, g1, bt1, m1, v1, hA, N);
    // layer 2
    k_gemmbf<HID_C, false><<<GB, 256, HID_C * 128 * 2, stream>>>(hA, Wt2, hB, N);
    k_aggbf<<<AB, 256, 0, stream>>>(hB, row_ptr, csr_src, dinv, b2, g2, bt2, m2, v2, hA, N);

    // pooling + classifier
    k_pool<<<(N + 63) / 64, 64, 0, stream>>>(hA, batch, pooled, N);
    k_final<<<1, 256, 0, stream>>>(batch, pooled, lw, lb, out, N);
}